// Round 7
// baseline (328.105 us; speedup 1.0000x reference)
//
#include <hip/hip_runtime.h>
#include <cstdint>

typedef unsigned short u16;
typedef __bf16 bf16x8 __attribute__((ext_vector_type(8)));
typedef float f32x4 __attribute__((ext_vector_type(4)));

#define T_SEQ 2048
#define NH 16

// RTNE float -> bf16 bits
__device__ __forceinline__ u16 f2bf(float f) {
  union { float f; uint32_t u; } x; x.f = f;
  uint32_t r = (x.u + 0x7fffu + ((x.u >> 16) & 1u)) >> 16;
  return (u16)r;
}

__device__ __forceinline__ float bf2f(u16 b) {
  union { uint32_t u; float f; } x; x.u = ((uint32_t)b) << 16; return x.f;
}

// pack two floats -> two bf16 (RTNE)
__device__ __forceinline__ uint32_t pk2bf(float a, float b) {
  union { float f; uint32_t u; } x, y; x.f = a; y.f = b;
  uint32_t lo = (x.u + 0x7fffu + ((x.u >> 16) & 1u)) >> 16;
  uint32_t hi = (y.u + 0x7fffu + ((y.u >> 16) & 1u)) >> 16;
  return lo | (hi << 16);
}

// stage 8 contiguous fp32 -> 8 bf16 in LDS (one uint4 write)
__device__ __forceinline__ void stage8_f32(u16* dst, const float* src) {
  float4 a = *(const float4*)src;
  float4 b = *(const float4*)(src + 4);
  uint4 o;
  o.x = pk2bf(a.x, a.y); o.y = pk2bf(a.z, a.w);
  o.z = pk2bf(b.x, b.y); o.w = pk2bf(b.z, b.w);
  *(uint4*)dst = o;
}

// C[M,N] = A[M,K] * W[N,K]^T. A fp32 or bf16; W fp32; C fp32 OR bf16 (CF32).
// tile 128x128, BK=64, 256 threads = 4 waves 2x2, each wave 64x64 via 4x4 MFMA tiles
template <bool AF32, bool CF32>
__global__ __launch_bounds__(256) void gemm_bt(
    const void* __restrict__ Ap, const float* __restrict__ W,
    void* __restrict__ Cp, int M, int N, int K) {
  __shared__ __align__(16) u16 As[128 * 72];
  __shared__ __align__(16) u16 Bs[128 * 72];
  const int tid  = threadIdx.x;
  const int n0   = blockIdx.x * 128;
  const int m0   = blockIdx.y * 128;
  const int lane = tid & 63;
  const int wave = tid >> 6;
  const int wm   = (wave >> 1) * 64;
  const int wn   = (wave & 1) * 64;
  const int l15  = lane & 15;
  const int quad = lane >> 4;
  const int t8   = tid & 7;
  const int rowb = tid >> 3;

  f32x4 acc[4][4];
#pragma unroll
  for (int i = 0; i < 4; i++)
#pragma unroll
    for (int j = 0; j < 4; j++) acc[i][j] = (f32x4){0.f, 0.f, 0.f, 0.f};

  for (int k0 = 0; k0 < K; k0 += 64) {
    __syncthreads();
#pragma unroll
    for (int r = 0; r < 4; r++) {
      int row = rowb + r * 32;
      if constexpr (AF32)
        stage8_f32(&As[row * 72 + t8 * 8],
                   (const float*)Ap + (size_t)(m0 + row) * K + k0 + t8 * 8);
      else
        *(uint4*)&As[row * 72 + t8 * 8] =
            *(const uint4*)((const u16*)Ap + (size_t)(m0 + row) * K + k0 + t8 * 8);
      stage8_f32(&Bs[row * 72 + t8 * 8], W + (size_t)(n0 + row) * K + k0 + t8 * 8);
    }
    __syncthreads();
#pragma unroll
    for (int kk = 0; kk < 64; kk += 32) {
      bf16x8 af[4], bfr[4];
#pragma unroll
      for (int i = 0; i < 4; i++)
        af[i] = *(const bf16x8*)&As[(wm + i * 16 + l15) * 72 + kk + quad * 8];
#pragma unroll
      for (int j = 0; j < 4; j++)
        bfr[j] = *(const bf16x8*)&Bs[(wn + j * 16 + l15) * 72 + kk + quad * 8];
#pragma unroll
      for (int i = 0; i < 4; i++)
#pragma unroll
        for (int j = 0; j < 4; j++)
          acc[i][j] = __builtin_amdgcn_mfma_f32_16x16x32_bf16(af[i], bfr[j], acc[i][j], 0, 0, 0);
    }
  }
#pragma unroll
  for (int i = 0; i < 4; i++)
#pragma unroll
    for (int j = 0; j < 4; j++)
#pragma unroll
      for (int r = 0; r < 4; r++) {
        int row = m0 + wm + i * 16 + quad * 4 + r;
        int col = n0 + wn + j * 16 + l15;
        if constexpr (CF32)
          ((float*)Cp)[(size_t)row * N + col] = acc[i][j][r];
        else
          ((u16*)Cp)[(size_t)row * N + col] = f2bf(acc[i][j][r]);
      }
}

// k,v slices of qkv ws (bf16 cols 1024..3071) -> fp32 outputs
__global__ __launch_bounds__(256) void copy_kv(const u16* __restrict__ qkv,
                                               float* __restrict__ outk,
                                               float* __restrict__ outv) {
  int m = blockIdx.x;
  int tid = threadIdx.x;
  const u16* src = qkv + (size_t)m * 3072;
  float* dst; int c;
  if (tid < 128) { dst = outk + (size_t)m * 1024; c = tid * 8; }
  else           { dst = outv + (size_t)m * 1024; c = (tid - 128) * 8; }
  const u16* s = (tid < 128) ? src + 1024 + c : src + 2048 + c;
  float4 f0, f1;
  f0.x = bf2f(s[0]); f0.y = bf2f(s[1]); f0.z = bf2f(s[2]); f0.w = bf2f(s[3]);
  f1.x = bf2f(s[4]); f1.y = bf2f(s[5]); f1.z = bf2f(s[6]); f1.w = bf2f(s[7]);
  *(float4*)&dst[c] = f0;
  *(float4*)&dst[c + 4] = f1;
}

// vt[(b*NH+h)*64 + d][t] = v[b,t,h,d]   (64x64 LDS tile transpose, bf16 ws)
__global__ __launch_bounds__(256) void transpose_v(const u16* __restrict__ qkv,
                                                   u16* __restrict__ vt) {
  __shared__ __align__(16) u16 tile[64 * 72];
  int t0 = blockIdx.x * 64;
  int bh = blockIdx.y;
  int b = bh >> 4, h = bh & 15;
  int tid = threadIdx.x;
  int t8 = tid & 7, rowb = tid >> 3;
#pragma unroll
  for (int r = 0; r < 2; r++) {
    int row = rowb + r * 32;
    *(uint4*)&tile[row * 72 + t8 * 8] =
        *(const uint4*)&qkv[((size_t)b * T_SEQ + t0 + row) * 3072 + 2048 + h * 64 + t8 * 8];
  }
  __syncthreads();
#pragma unroll
  for (int r = 0; r < 2; r++) {
    int d = rowb + r * 32;
    union { u16 s[8]; uint4 u; } tmp;
#pragma unroll
    for (int e = 0; e < 8; e++) tmp.s[e] = tile[(t8 * 8 + e) * 72 + d];
    *(uint4*)&vt[((size_t)(b * NH + h) * 64 + d) * 2048 + t0 + t8 * 8] = tmp.u;
  }
}

// Flash-style causal attention. grid (16 q-tiles, 32 bh); 4 waves, 32 q-rows each.
__global__ __launch_bounds__(256) void attn(const u16* __restrict__ qkv,
                                            const u16* __restrict__ vt,
                                            u16* __restrict__ o) {
  __shared__ __align__(16) u16 Qs[128 * 72];
  __shared__ __align__(16) u16 Ks[64 * 72];
  __shared__ __align__(16) u16 Vts[64 * 72];
  __shared__ __align__(16) u16 Ps[4][32 * 72];

  const int tid = threadIdx.x;
  const int qt = blockIdx.x;
  const int bh = blockIdx.y;
  const int b = bh >> 4, h = bh & 15;
  const int q0 = qt * 128;
  const int lane = tid & 63, wave = tid >> 6;
  const int l15 = lane & 15, quad = lane >> 4;
  const int t8 = tid & 7, rowb = tid >> 3;

  const size_t qbase = (size_t)b * T_SEQ * 3072;

#pragma unroll
  for (int r = 0; r < 4; r++) {
    int row = rowb + r * 32;
    *(uint4*)&Qs[row * 72 + t8 * 8] =
        *(const uint4*)&qkv[qbase + (size_t)(q0 + row) * 3072 + h * 64 + t8 * 8];
  }

  f32x4 acc_o[2][4];
#pragma unroll
  for (int i = 0; i < 2; i++)
#pragma unroll
    for (int n = 0; n < 4; n++) acc_o[i][n] = (f32x4){0.f, 0.f, 0.f, 0.f};
  float mrow[8], lrow[8];
#pragma unroll
  for (int i = 0; i < 8; i++) { mrow[i] = -1e30f; lrow[i] = 0.f; }

  const int wq0 = q0 + wave * 32;
  const int ktiles = (q0 + 128) / 64;

  for (int kt = 0; kt < ktiles; kt++) {
    const int k0 = kt * 64;
    __syncthreads();
#pragma unroll
    for (int r = 0; r < 2; r++) {
      int row = rowb + r * 32;
      *(uint4*)&Ks[row * 72 + t8 * 8] =
          *(const uint4*)&qkv[qbase + (size_t)(k0 + row) * 3072 + 1024 + h * 64 + t8 * 8];
      *(uint4*)&Vts[row * 72 + t8 * 8] =
          *(const uint4*)&vt[((size_t)(b * NH + h) * 64 + row) * 2048 + k0 + t8 * 8];
    }
    __syncthreads();

    const bool active = (k0 < wq0 + 32);

    if (active) {
      f32x4 sacc[2][4];
#pragma unroll
      for (int i = 0; i < 2; i++)
#pragma unroll
        for (int j = 0; j < 4; j++) sacc[i][j] = (f32x4){0.f, 0.f, 0.f, 0.f};
#pragma unroll
      for (int kk = 0; kk < 64; kk += 32) {
        bf16x8 qf[2], kf[4];
#pragma unroll
        for (int i = 0; i < 2; i++)
          qf[i] = *(const bf16x8*)&Qs[(wave * 32 + i * 16 + l15) * 72 + kk + quad * 8];
#pragma unroll
        for (int j = 0; j < 4; j++)
          kf[j] = *(const bf16x8*)&Ks[(j * 16 + l15) * 72 + kk + quad * 8];
#pragma unroll
        for (int i = 0; i < 2; i++)
#pragma unroll
          for (int j = 0; j < 4; j++)
            sacc[i][j] = __builtin_amdgcn_mfma_f32_16x16x32_bf16(qf[i], kf[j], sacc[i][j], 0, 0, 0);
      }

      const bool diag = (k0 + 63 > wq0);
#pragma unroll
      for (int i = 0; i < 2; i++)
#pragma unroll
        for (int j = 0; j < 4; j++)
#pragma unroll
          for (int r = 0; r < 4; r++) {
            float s = sacc[i][j][r] * 0.125f;
            if (diag) {
              int row = wq0 + i * 16 + quad * 4 + r;
              int col = k0 + j * 16 + l15;
              if (col > row) s = -1e30f;
            }
            sacc[i][j][r] = s;
          }

#pragma unroll
      for (int i = 0; i < 2; i++)
#pragma unroll
        for (int r = 0; r < 4; r++) {
          float mx = sacc[i][0][r];
#pragma unroll
          for (int j = 1; j < 4; j++) mx = fmaxf(mx, sacc[i][j][r]);
#pragma unroll
          for (int off = 1; off < 16; off <<= 1) mx = fmaxf(mx, __shfl_xor(mx, off));
          const int id = i * 4 + r;
          float mnew = fmaxf(mrow[id], mx);
          float alpha = __expf(mrow[id] - mnew);
          float sum = 0.f;
#pragma unroll
          for (int j = 0; j < 4; j++) {
            float p = __expf(sacc[i][j][r] - mnew);
            sacc[i][j][r] = p;
            sum += p;
          }
#pragma unroll
          for (int off = 1; off < 16; off <<= 1) sum += __shfl_xor(sum, off);
          lrow[id] = lrow[id] * alpha + sum;
          mrow[id] = mnew;
#pragma unroll
          for (int n = 0; n < 4; n++) acc_o[i][n][r] *= alpha;
        }

#pragma unroll
      for (int i = 0; i < 2; i++)
#pragma unroll
        for (int j = 0; j < 4; j++)
#pragma unroll
          for (int r = 0; r < 4; r++)
            Ps[wave][(i * 16 + quad * 4 + r) * 72 + j * 16 + l15] = f2bf(sacc[i][j][r]);
    }

    __syncthreads();  // fence between u16 P-stores and bf16x8 P-loads

    if (active) {
#pragma unroll
      for (int ks = 0; ks < 64; ks += 32) {
        bf16x8 pf[2], vf[4];
#pragma unroll
        for (int i = 0; i < 2; i++)
          pf[i] = *(const bf16x8*)&Ps[wave][(i * 16 + l15) * 72 + ks + quad * 8];
#pragma unroll
        for (int n = 0; n < 4; n++)
          vf[n] = *(const bf16x8*)&Vts[(n * 16 + l15) * 72 + ks + quad * 8];
#pragma unroll
        for (int i = 0; i < 2; i++)
#pragma unroll
          for (int n = 0; n < 4; n++)
            acc_o[i][n] = __builtin_amdgcn_mfma_f32_16x16x32_bf16(pf[i], vf[n], acc_o[i][n], 0, 0, 0);
      }
    }
  }

#pragma unroll
  for (int i = 0; i < 2; i++)
#pragma unroll
    for (int r = 0; r < 4; r++) {
      float inv = 1.0f / lrow[i * 4 + r];
      int row = wq0 + i * 16 + quad * 4 + r;
#pragma unroll
      for (int n = 0; n < 4; n++)
        o[(size_t)(b * T_SEQ + row) * 1024 + h * 64 + n * 16 + l15] =
            f2bf(acc_o[i][n][r] * inv);
    }
}

extern "C" void kernel_launch(void* const* d_in, const int* in_sizes, int n_in,
                              void* d_out, int out_size, void* d_ws, size_t ws_size,
                              hipStream_t stream) {
  const float* x     = (const float*)d_in[0];   // (2,2048,1024) fp32
  const float* w_qkv = (const float*)d_in[1];   // (3072,1024)   fp32
  const float* w_o   = (const float*)d_in[2];   // (1024,1024)   fp32
  float* out  = (float*)d_out;                  // fp32 (4096,1024)
  float* outk = out + (size_t)4194304;          // fp32 (2,2048,16,64)
  float* outv = out + (size_t)8388608;

  u16* qkv = (u16*)d_ws;                        // 4096*3072 bf16 (25.2 MB)
  u16* vt  = qkv + (size_t)4096 * 3072;         // 32*64*2048 bf16 (8.4 MB)
  u16* ao  = vt + (size_t)4194304;              // 4096*1024 bf16 (8.4 MB)

  // 1. qkv(bf16 ws) = bf16(x) @ bf16(w_qkv)^T
  gemm_bt<true, false><<<dim3(24, 32), 256, 0, stream>>>(x, w_qkv, qkv, 4096, 3072, 1024);
  // 2. k,v -> fp32 outputs
  copy_kv<<<4096, 256, 0, stream>>>(qkv, outk, outv);
  // 3. v -> v^T ws
  transpose_v<<<dim3(32, 32), 256, 0, stream>>>(qkv, vt);
  // 4. flash attention -> ao (bf16 ws)
  attn<<<dim3(16, 32), 256, 0, stream>>>(qkv, vt, ao);
  // 5. out(fp32) = ao @ bf16(w_o)^T
  gemm_bt<false, true><<<dim3(8, 32), 256, 0, stream>>>(ao, w_o, out, 4096, 1024, 1024);
}

// Round 8
// 326.871 us; speedup vs baseline: 1.0038x; 1.0038x over previous
//
#include <hip/hip_runtime.h>
#include <cstdint>

typedef unsigned short u16;
typedef __bf16 bf16x8 __attribute__((ext_vector_type(8)));
typedef float f32x4 __attribute__((ext_vector_type(4)));

#define T_SEQ 2048
#define NH 16

// RTNE float -> bf16 bits
__device__ __forceinline__ u16 f2bf(float f) {
  union { float f; uint32_t u; } x; x.f = f;
  uint32_t r = (x.u + 0x7fffu + ((x.u >> 16) & 1u)) >> 16;
  return (u16)r;
}

__device__ __forceinline__ float bf2f(u16 b) {
  union { uint32_t u; float f; } x; x.u = ((uint32_t)b) << 16; return x.f;
}

// pack two floats -> two bf16 (RTNE)
__device__ __forceinline__ uint32_t pk2bf(float a, float b) {
  union { float f; uint32_t u; } x, y; x.f = a; y.f = b;
  uint32_t lo = (x.u + 0x7fffu + ((x.u >> 16) & 1u)) >> 16;
  uint32_t hi = (y.u + 0x7fffu + ((y.u >> 16) & 1u)) >> 16;
  return lo | (hi << 16);
}

// stage 8 contiguous fp32 -> 8 bf16 in LDS (one uint4 write)
__device__ __forceinline__ void stage8_f32(u16* dst, const float* src) {
  float4 a = *(const float4*)src;
  float4 b = *(const float4*)(src + 4);
  uint4 o;
  o.x = pk2bf(a.x, a.y); o.y = pk2bf(a.z, a.w);
  o.z = pk2bf(b.x, b.y); o.w = pk2bf(b.z, b.w);
  *(uint4*)dst = o;
}

// C[M,N] = A[M,K] * W[N,K]^T. A fp32 or bf16; W fp32; C fp32 (CF32) or bf16 ws.
// If outk != nullptr: blocks with cols>=1024 additionally write fp32 k/v outputs.
// tile 128x128, BK=64, 256 threads = 4 waves 2x2, each wave 64x64 via 4x4 MFMA tiles
template <bool AF32, bool CF32>
__global__ __launch_bounds__(256) void gemm_bt(
    const void* __restrict__ Ap, const float* __restrict__ W,
    void* __restrict__ Cp, float* __restrict__ outk, float* __restrict__ outv,
    int M, int N, int K) {
  __shared__ __align__(16) u16 As[128 * 72];
  __shared__ __align__(16) u16 Bs[128 * 72];
  const int tid  = threadIdx.x;
  const int n0   = blockIdx.x * 128;
  const int m0   = blockIdx.y * 128;
  const int lane = tid & 63;
  const int wave = tid >> 6;
  const int wm   = (wave >> 1) * 64;
  const int wn   = (wave & 1) * 64;
  const int l15  = lane & 15;
  const int quad = lane >> 4;
  const int t8   = tid & 7;
  const int rowb = tid >> 3;

  f32x4 acc[4][4];
#pragma unroll
  for (int i = 0; i < 4; i++)
#pragma unroll
    for (int j = 0; j < 4; j++) acc[i][j] = (f32x4){0.f, 0.f, 0.f, 0.f};

  for (int k0 = 0; k0 < K; k0 += 64) {
    __syncthreads();
#pragma unroll
    for (int r = 0; r < 4; r++) {
      int row = rowb + r * 32;
      if constexpr (AF32)
        stage8_f32(&As[row * 72 + t8 * 8],
                   (const float*)Ap + (size_t)(m0 + row) * K + k0 + t8 * 8);
      else
        *(uint4*)&As[row * 72 + t8 * 8] =
            *(const uint4*)((const u16*)Ap + (size_t)(m0 + row) * K + k0 + t8 * 8);
      stage8_f32(&Bs[row * 72 + t8 * 8], W + (size_t)(n0 + row) * K + k0 + t8 * 8);
    }
    __syncthreads();
#pragma unroll
    for (int kk = 0; kk < 64; kk += 32) {
      bf16x8 af[4], bfr[4];
#pragma unroll
      for (int i = 0; i < 4; i++)
        af[i] = *(const bf16x8*)&As[(wm + i * 16 + l15) * 72 + kk + quad * 8];
#pragma unroll
      for (int j = 0; j < 4; j++)
        bfr[j] = *(const bf16x8*)&Bs[(wn + j * 16 + l15) * 72 + kk + quad * 8];
#pragma unroll
      for (int i = 0; i < 4; i++)
#pragma unroll
        for (int j = 0; j < 4; j++)
          acc[i][j] = __builtin_amdgcn_mfma_f32_16x16x32_bf16(af[i], bfr[j], acc[i][j], 0, 0, 0);
    }
  }
#pragma unroll
  for (int i = 0; i < 4; i++)
#pragma unroll
    for (int j = 0; j < 4; j++)
#pragma unroll
      for (int r = 0; r < 4; r++) {
        int row = m0 + wm + i * 16 + quad * 4 + r;
        int col = n0 + wn + j * 16 + l15;
        float v = acc[i][j][r];
        if constexpr (CF32) {
          ((float*)Cp)[(size_t)row * N + col] = v;
        } else {
          ((u16*)Cp)[(size_t)row * N + col] = f2bf(v);
          if (outk) {  // uniform per launch; col class uniform per block (n0 mult of 128)
            if (col >= 2048)      outv[(size_t)row * 1024 + (col - 2048)] = v;
            else if (col >= 1024) outk[(size_t)row * 1024 + (col - 1024)] = v;
          }
        }
      }
}

// vt[(b*NH+h)*64 + d][t] = v[b,t,h,d]   (64x64 LDS tile transpose, bf16 ws)
__global__ __launch_bounds__(256) void transpose_v(const u16* __restrict__ qkv,
                                                   u16* __restrict__ vt) {
  __shared__ __align__(16) u16 tile[64 * 72];
  int t0 = blockIdx.x * 64;
  int bh = blockIdx.y;
  int b = bh >> 4, h = bh & 15;
  int tid = threadIdx.x;
  int t8 = tid & 7, rowb = tid >> 3;
#pragma unroll
  for (int r = 0; r < 2; r++) {
    int row = rowb + r * 32;
    *(uint4*)&tile[row * 72 + t8 * 8] =
        *(const uint4*)&qkv[((size_t)b * T_SEQ + t0 + row) * 3072 + 2048 + h * 64 + t8 * 8];
  }
  __syncthreads();
#pragma unroll
  for (int r = 0; r < 2; r++) {
    int d = rowb + r * 32;
    union { u16 s[8]; uint4 u; } tmp;
#pragma unroll
    for (int e = 0; e < 8; e++) tmp.s[e] = tile[(t8 * 8 + e) * 72 + d];
    *(uint4*)&vt[((size_t)(b * NH + h) * 64 + d) * 2048 + t0 + t8 * 8] = tmp.u;
  }
}

// Flash-style causal attention, load-balanced.
// grid (16 pairs, 32 bh). Block processes q-tile pair (j, 31-j) of 64 rows each,
// sequentially -> every block does exactly 33 k-tiles (uniform).
// 4 waves x 16 q-rows; k-tile = 64 keys; no wave is ever fully masked.
__global__ __launch_bounds__(256) void attn(const u16* __restrict__ qkv,
                                            const u16* __restrict__ vt,
                                            u16* __restrict__ o) {
  __shared__ __align__(16) u16 Qs[64 * 72];
  __shared__ __align__(16) u16 Ks[64 * 72];
  __shared__ __align__(16) u16 Vts[64 * 72];
  __shared__ __align__(16) u16 Ps[4][16 * 72];

  const int tid = threadIdx.x;
  const int pair = blockIdx.x;       // 0..15
  const int bh = blockIdx.y;
  const int b = bh >> 4, h = bh & 15;
  const int lane = tid & 63, wave = tid >> 6;
  const int l15 = lane & 15, quad = lane >> 4;
  const int t8 = tid & 7, rowb = tid >> 3;
  const size_t qbase = (size_t)b * T_SEQ * 3072;
  const size_t vbase = (size_t)(b * NH + h) * 64 * 2048;

#pragma unroll
  for (int p = 0; p < 2; p++) {
    const int qt = p ? (31 - pair) : pair;   // phase q-tile
    const int q0 = qt * 64;
    __syncthreads();  // all waves done with previous phase's LDS
    // stage Q (64 x 64)
#pragma unroll
    for (int r = 0; r < 2; r++) {
      int row = rowb + r * 32;
      *(uint4*)&Qs[row * 72 + t8 * 8] =
          *(const uint4*)&qkv[qbase + (size_t)(q0 + row) * 3072 + h * 64 + t8 * 8];
    }

    f32x4 acc_o[4];
#pragma unroll
    for (int n = 0; n < 4; n++) acc_o[n] = (f32x4){0.f, 0.f, 0.f, 0.f};
    float mrow[4], lrow[4];
#pragma unroll
    for (int r = 0; r < 4; r++) { mrow[r] = -1e30f; lrow[r] = 0.f; }

    const int wq0 = q0 + wave * 16;
    const int ktiles = qt + 1;

    for (int kt = 0; kt < ktiles; kt++) {
      const int k0 = kt * 64;
      __syncthreads();
#pragma unroll
      for (int r = 0; r < 2; r++) {
        int row = rowb + r * 32;
        *(uint4*)&Ks[row * 72 + t8 * 8] =
            *(const uint4*)&qkv[qbase + (size_t)(k0 + row) * 3072 + 1024 + h * 64 + t8 * 8];
        *(uint4*)&Vts[row * 72 + t8 * 8] =
            *(const uint4*)&vt[vbase + (size_t)row * 2048 + k0 + t8 * 8];
      }
      __syncthreads();

      // S = Q K^T  (16 x 64 per wave)
      f32x4 sacc[4];
#pragma unroll
      for (int j = 0; j < 4; j++) sacc[j] = (f32x4){0.f, 0.f, 0.f, 0.f};
#pragma unroll
      for (int kk = 0; kk < 64; kk += 32) {
        bf16x8 qf = *(const bf16x8*)&Qs[(wave * 16 + l15) * 72 + kk + quad * 8];
        bf16x8 kf[4];
#pragma unroll
        for (int j = 0; j < 4; j++)
          kf[j] = *(const bf16x8*)&Ks[(j * 16 + l15) * 72 + kk + quad * 8];
#pragma unroll
        for (int j = 0; j < 4; j++)
          sacc[j] = __builtin_amdgcn_mfma_f32_16x16x32_bf16(qf, kf[j], sacc[j], 0, 0, 0);
      }

      const bool diag = (kt == qt);
#pragma unroll
      for (int j = 0; j < 4; j++)
#pragma unroll
        for (int r = 0; r < 4; r++) {
          float s = sacc[j][r] * 0.125f;
          if (diag) {
            int row = wq0 + quad * 4 + r;
            int col = k0 + j * 16 + l15;
            if (col > row) s = -1e30f;
          }
          sacc[j][r] = s;
        }

      // online softmax; lane owns rows quad*4 + r
#pragma unroll
      for (int r = 0; r < 4; r++) {
        float mx = sacc[0][r];
#pragma unroll
        for (int j = 1; j < 4; j++) mx = fmaxf(mx, sacc[j][r]);
#pragma unroll
        for (int off = 1; off < 16; off <<= 1) mx = fmaxf(mx, __shfl_xor(mx, off));
        float mnew = fmaxf(mrow[r], mx);
        float alpha = __expf(mrow[r] - mnew);
        float sum = 0.f;
#pragma unroll
        for (int j = 0; j < 4; j++) {
          float pv = __expf(sacc[j][r] - mnew);
          sacc[j][r] = pv;
          sum += pv;
        }
#pragma unroll
        for (int off = 1; off < 16; off <<= 1) sum += __shfl_xor(sum, off);
        lrow[r] = lrow[r] * alpha + sum;
        mrow[r] = mnew;
#pragma unroll
        for (int n = 0; n < 4; n++) acc_o[n][r] *= alpha;
      }

      // P (C-layout) -> per-wave LDS
#pragma unroll
      for (int j = 0; j < 4; j++)
#pragma unroll
        for (int r = 0; r < 4; r++)
          Ps[wave][(quad * 4 + r) * 72 + j * 16 + l15] = f2bf(sacc[j][r]);

      __syncthreads();  // fence: u16 P-stores -> bf16x8 P-loads (proven pattern)

      // O += P * V
#pragma unroll
      for (int ks = 0; ks < 64; ks += 32) {
        bf16x8 pf = *(const bf16x8*)&Ps[wave][l15 * 72 + ks + quad * 8];
        bf16x8 vf[4];
#pragma unroll
        for (int n = 0; n < 4; n++)
          vf[n] = *(const bf16x8*)&Vts[(n * 16 + l15) * 72 + ks + quad * 8];
#pragma unroll
        for (int n = 0; n < 4; n++)
          acc_o[n] = __builtin_amdgcn_mfma_f32_16x16x32_bf16(pf, vf[n], acc_o[n], 0, 0, 0);
      }
    }

    // epilogue: O /= l, write bf16 ws
#pragma unroll
    for (int r = 0; r < 4; r++) {
      float inv = 1.0f / lrow[r];
      int row = wq0 + quad * 4 + r;
#pragma unroll
      for (int n = 0; n < 4; n++)
        o[(size_t)(b * T_SEQ + row) * 1024 + h * 64 + n * 16 + l15] =
            f2bf(acc_o[n][r] * inv);
    }
  }
}

extern "C" void kernel_launch(void* const* d_in, const int* in_sizes, int n_in,
                              void* d_out, int out_size, void* d_ws, size_t ws_size,
                              hipStream_t stream) {
  const float* x     = (const float*)d_in[0];   // (2,2048,1024) fp32
  const float* w_qkv = (const float*)d_in[1];   // (3072,1024)   fp32
  const float* w_o   = (const float*)d_in[2];   // (1024,1024)   fp32
  float* out  = (float*)d_out;                  // fp32 (4096,1024)
  float* outk = out + (size_t)4194304;          // fp32 (2,2048,16,64)
  float* outv = out + (size_t)8388608;

  u16* qkv = (u16*)d_ws;                        // 4096*3072 bf16 (25.2 MB)
  u16* vt  = qkv + (size_t)4096 * 3072;         // 32*64*2048 bf16 (8.4 MB)
  u16* ao  = vt + (size_t)4194304;              // 4096*1024 bf16 (8.4 MB)

  // 1. qkv(bf16 ws) = bf16(x) @ bf16(w_qkv)^T; k/v cols also -> fp32 outputs
  gemm_bt<true, false><<<dim3(24, 32), 256, 0, stream>>>(
      x, w_qkv, qkv, outk, outv, 4096, 3072, 1024);
  // 2. v -> v^T ws
  transpose_v<<<dim3(32, 32), 256, 0, stream>>>(qkv, vt);
  // 3. flash attention -> ao (bf16 ws), balanced pairs
  attn<<<dim3(16, 32), 256, 0, stream>>>(qkv, vt, ao);
  // 4. out(fp32) = ao @ bf16(w_o)^T
  gemm_bt<false, true><<<dim3(8, 32), 256, 0, stream>>>(
      ao, w_o, out, nullptr, nullptr, 4096, 1024, 1024);
}

// Round 9
// 245.172 us; speedup vs baseline: 1.3383x; 1.3332x over previous
//
#include <hip/hip_runtime.h>
#include <cstdint>

typedef unsigned short u16;
typedef __bf16 bf16x8 __attribute__((ext_vector_type(8)));
typedef float f32x4 __attribute__((ext_vector_type(4)));

#define T_SEQ 2048
#define NH 16

// RTNE float -> bf16 bits
__device__ __forceinline__ u16 f2bf(float f) {
  union { float f; uint32_t u; } x; x.f = f;
  uint32_t r = (x.u + 0x7fffu + ((x.u >> 16) & 1u)) >> 16;
  return (u16)r;
}

__device__ __forceinline__ float bf2f(u16 b) {
  union { uint32_t u; float f; } x; x.u = ((uint32_t)b) << 16; return x.f;
}

// pack two floats -> two bf16 (RTNE)
__device__ __forceinline__ uint32_t pk2bf(float a, float b) {
  union { float f; uint32_t u; } x, y; x.f = a; y.f = b;
  uint32_t lo = (x.u + 0x7fffu + ((x.u >> 16) & 1u)) >> 16;
  uint32_t hi = (y.u + 0x7fffu + ((y.u >> 16) & 1u)) >> 16;
  return lo | (hi << 16);
}

// 8 fp32 -> 8 bf16 (one uint4 store)
__device__ __forceinline__ void cvt8(u16* dst, const float* src) {
  float4 a = *(const float4*)src;
  float4 b = *(const float4*)(src + 4);
  uint4 o;
  o.x = pk2bf(a.x, a.y); o.y = pk2bf(a.z, a.w);
  o.z = pk2bf(b.x, b.y); o.w = pk2bf(b.z, b.w);
  *(uint4*)dst = o;
}

// grid-stride fp32 -> bf16, 8 elems/thread
__global__ __launch_bounds__(256) void cvt_f32_bf16(const float* __restrict__ src,
                                                    u16* __restrict__ dst, int n8) {
  int i = blockIdx.x * 256 + threadIdx.x;
  if (i < n8) cvt8(&dst[(size_t)i * 8], &src[(size_t)i * 8]);
}

// C[M,N] = A[M,K] * W[N,K]^T. A,W bf16; C fp32 (CF32) or bf16 ws.
// KV: blocks with cols>=1024 additionally write fp32 k/v outputs.
// tile 128x128, BK=64, 256 threads = 4 waves 2x2, each wave 64x64 via 4x4 MFMA tiles
template <bool CF32, bool KV>
__global__ __launch_bounds__(256) void gemm_bt(
    const u16* __restrict__ A, const u16* __restrict__ W,
    void* __restrict__ Cp, float* __restrict__ outk, float* __restrict__ outv,
    int M, int N, int K) {
  __shared__ __align__(16) u16 As[128 * 72];
  __shared__ __align__(16) u16 Bs[128 * 72];
  const int tid  = threadIdx.x;
  const int n0   = blockIdx.x * 128;
  const int m0   = blockIdx.y * 128;
  const int lane = tid & 63;
  const int wave = tid >> 6;
  const int wm   = (wave >> 1) * 64;
  const int wn   = (wave & 1) * 64;
  const int l15  = lane & 15;
  const int quad = lane >> 4;
  const int t8   = tid & 7;
  const int rowb = tid >> 3;

  f32x4 acc[4][4];
#pragma unroll
  for (int i = 0; i < 4; i++)
#pragma unroll
    for (int j = 0; j < 4; j++) acc[i][j] = (f32x4){0.f, 0.f, 0.f, 0.f};

  for (int k0 = 0; k0 < K; k0 += 64) {
    __syncthreads();
#pragma unroll
    for (int r = 0; r < 4; r++) {
      int row = rowb + r * 32;
      *(uint4*)&As[row * 72 + t8 * 8] =
          *(const uint4*)&A[(size_t)(m0 + row) * K + k0 + t8 * 8];
      *(uint4*)&Bs[row * 72 + t8 * 8] =
          *(const uint4*)&W[(size_t)(n0 + row) * K + k0 + t8 * 8];
    }
    __syncthreads();
#pragma unroll
    for (int kk = 0; kk < 64; kk += 32) {
      bf16x8 af[4], bfr[4];
#pragma unroll
      for (int i = 0; i < 4; i++)
        af[i] = *(const bf16x8*)&As[(wm + i * 16 + l15) * 72 + kk + quad * 8];
#pragma unroll
      for (int j = 0; j < 4; j++)
        bfr[j] = *(const bf16x8*)&Bs[(wn + j * 16 + l15) * 72 + kk + quad * 8];
#pragma unroll
      for (int i = 0; i < 4; i++)
#pragma unroll
        for (int j = 0; j < 4; j++)
          acc[i][j] = __builtin_amdgcn_mfma_f32_16x16x32_bf16(af[i], bfr[j], acc[i][j], 0, 0, 0);
    }
  }
#pragma unroll
  for (int i = 0; i < 4; i++)
#pragma unroll
    for (int j = 0; j < 4; j++)
#pragma unroll
      for (int r = 0; r < 4; r++) {
        int row = m0 + wm + i * 16 + quad * 4 + r;
        int col = n0 + wn + j * 16 + l15;
        float v = acc[i][j][r];
        if constexpr (CF32) {
          ((float*)Cp)[(size_t)row * N + col] = v;
        } else {
          ((u16*)Cp)[(size_t)row * N + col] = f2bf(v);
          if constexpr (KV) {
            if (col >= 2048)      outv[(size_t)row * 1024 + (col - 2048)] = v;
            else if (col >= 1024) outk[(size_t)row * 1024 + (col - 1024)] = v;
          }
        }
      }
}

// vt[(b*NH+h)*64 + d][t] = v[b,t,h,d]   (64x64 LDS tile transpose, bf16 ws)
__global__ __launch_bounds__(256) void transpose_v(const u16* __restrict__ qkv,
                                                   u16* __restrict__ vt) {
  __shared__ __align__(16) u16 tile[64 * 72];
  int t0 = blockIdx.x * 64;
  int bh = blockIdx.y;
  int b = bh >> 4, h = bh & 15;
  int tid = threadIdx.x;
  int t8 = tid & 7, rowb = tid >> 3;
#pragma unroll
  for (int r = 0; r < 2; r++) {
    int row = rowb + r * 32;
    *(uint4*)&tile[row * 72 + t8 * 8] =
        *(const uint4*)&qkv[((size_t)b * T_SEQ + t0 + row) * 3072 + 2048 + h * 64 + t8 * 8];
  }
  __syncthreads();
#pragma unroll
  for (int r = 0; r < 2; r++) {
    int d = rowb + r * 32;
    union { u16 s[8]; uint4 u; } tmp;
#pragma unroll
    for (int e = 0; e < 8; e++) tmp.s[e] = tile[(t8 * 8 + e) * 72 + d];
    *(uint4*)&vt[((size_t)(b * NH + h) * 64 + d) * 2048 + t0 + t8 * 8] = tmp.u;
  }
}

// Flash-style causal attention, load-balanced pairs (j, 31-j): 33 k-tiles/block.
__global__ __launch_bounds__(256) void attn(const u16* __restrict__ qkv,
                                            const u16* __restrict__ vt,
                                            u16* __restrict__ o) {
  __shared__ __align__(16) u16 Qs[64 * 72];
  __shared__ __align__(16) u16 Ks[64 * 72];
  __shared__ __align__(16) u16 Vts[64 * 72];
  __shared__ __align__(16) u16 Ps[4][16 * 72];

  const int tid = threadIdx.x;
  const int pair = blockIdx.x;
  const int bh = blockIdx.y;
  const int b = bh >> 4, h = bh & 15;
  const int lane = tid & 63, wave = tid >> 6;
  const int l15 = lane & 15, quad = lane >> 4;
  const int t8 = tid & 7, rowb = tid >> 3;
  const size_t qbase = (size_t)b * T_SEQ * 3072;
  const size_t vbase = (size_t)(b * NH + h) * 64 * 2048;

#pragma unroll
  for (int p = 0; p < 2; p++) {
    const int qt = p ? (31 - pair) : pair;
    const int q0 = qt * 64;
    __syncthreads();
#pragma unroll
    for (int r = 0; r < 2; r++) {
      int row = rowb + r * 32;
      *(uint4*)&Qs[row * 72 + t8 * 8] =
          *(const uint4*)&qkv[qbase + (size_t)(q0 + row) * 3072 + h * 64 + t8 * 8];
    }

    f32x4 acc_o[4];
#pragma unroll
    for (int n = 0; n < 4; n++) acc_o[n] = (f32x4){0.f, 0.f, 0.f, 0.f};
    float mrow[4], lrow[4];
#pragma unroll
    for (int r = 0; r < 4; r++) { mrow[r] = -1e30f; lrow[r] = 0.f; }

    const int wq0 = q0 + wave * 16;
    const int ktiles = qt + 1;

    for (int kt = 0; kt < ktiles; kt++) {
      const int k0 = kt * 64;
      __syncthreads();
#pragma unroll
      for (int r = 0; r < 2; r++) {
        int row = rowb + r * 32;
        *(uint4*)&Ks[row * 72 + t8 * 8] =
            *(const uint4*)&qkv[qbase + (size_t)(k0 + row) * 3072 + 1024 + h * 64 + t8 * 8];
        *(uint4*)&Vts[row * 72 + t8 * 8] =
            *(const uint4*)&vt[vbase + (size_t)row * 2048 + k0 + t8 * 8];
      }
      __syncthreads();

      f32x4 sacc[4];
#pragma unroll
      for (int j = 0; j < 4; j++) sacc[j] = (f32x4){0.f, 0.f, 0.f, 0.f};
#pragma unroll
      for (int kk = 0; kk < 64; kk += 32) {
        bf16x8 qf = *(const bf16x8*)&Qs[(wave * 16 + l15) * 72 + kk + quad * 8];
        bf16x8 kf[4];
#pragma unroll
        for (int j = 0; j < 4; j++)
          kf[j] = *(const bf16x8*)&Ks[(j * 16 + l15) * 72 + kk + quad * 8];
#pragma unroll
        for (int j = 0; j < 4; j++)
          sacc[j] = __builtin_amdgcn_mfma_f32_16x16x32_bf16(qf, kf[j], sacc[j], 0, 0, 0);
      }

      const bool diag = (kt == qt);
#pragma unroll
      for (int j = 0; j < 4; j++)
#pragma unroll
        for (int r = 0; r < 4; r++) {
          float s = sacc[j][r] * 0.125f;
          if (diag) {
            int row = wq0 + quad * 4 + r;
            int col = k0 + j * 16 + l15;
            if (col > row) s = -1e30f;
          }
          sacc[j][r] = s;
        }

#pragma unroll
      for (int r = 0; r < 4; r++) {
        float mx = sacc[0][r];
#pragma unroll
        for (int j = 1; j < 4; j++) mx = fmaxf(mx, sacc[j][r]);
#pragma unroll
        for (int off = 1; off < 16; off <<= 1) mx = fmaxf(mx, __shfl_xor(mx, off));
        float mnew = fmaxf(mrow[r], mx);
        float alpha = __expf(mrow[r] - mnew);
        float sum = 0.f;
#pragma unroll
        for (int j = 0; j < 4; j++) {
          float pv = __expf(sacc[j][r] - mnew);
          sacc[j][r] = pv;
          sum += pv;
        }
#pragma unroll
        for (int off = 1; off < 16; off <<= 1) sum += __shfl_xor(sum, off);
        lrow[r] = lrow[r] * alpha + sum;
        mrow[r] = mnew;
#pragma unroll
        for (int n = 0; n < 4; n++) acc_o[n][r] *= alpha;
      }

#pragma unroll
      for (int j = 0; j < 4; j++)
#pragma unroll
        for (int r = 0; r < 4; r++)
          Ps[wave][(quad * 4 + r) * 72 + j * 16 + l15] = f2bf(sacc[j][r]);

      __syncthreads();  // fence: u16 P-stores -> bf16x8 P-loads

#pragma unroll
      for (int ks = 0; ks < 64; ks += 32) {
        bf16x8 pf = *(const bf16x8*)&Ps[wave][l15 * 72 + ks + quad * 8];
        bf16x8 vf[4];
#pragma unroll
        for (int n = 0; n < 4; n++)
          vf[n] = *(const bf16x8*)&Vts[(n * 16 + l15) * 72 + ks + quad * 8];
#pragma unroll
        for (int n = 0; n < 4; n++)
          acc_o[n] = __builtin_amdgcn_mfma_f32_16x16x32_bf16(pf, vf[n], acc_o[n], 0, 0, 0);
      }
    }

#pragma unroll
    for (int r = 0; r < 4; r++) {
      float inv = 1.0f / lrow[r];
      int row = wq0 + quad * 4 + r;
#pragma unroll
      for (int n = 0; n < 4; n++)
        o[(size_t)(b * T_SEQ + row) * 1024 + h * 64 + n * 16 + l15] =
            f2bf(acc_o[n][r] * inv);
    }
  }
}

extern "C" void kernel_launch(void* const* d_in, const int* in_sizes, int n_in,
                              void* d_out, int out_size, void* d_ws, size_t ws_size,
                              hipStream_t stream) {
  const float* x     = (const float*)d_in[0];   // (2,2048,1024) fp32
  const float* w_qkv = (const float*)d_in[1];   // (3072,1024)   fp32
  const float* w_o   = (const float*)d_in[2];   // (1024,1024)   fp32
  float* out  = (float*)d_out;                  // fp32 (4096,1024)
  float* outk = out + (size_t)4194304;
  float* outv = out + (size_t)8388608;

  u16* qkv = (u16*)d_ws;                        // 4096*3072
  u16* vt  = qkv + (size_t)4096 * 3072;         // 32*64*2048
  u16* ao  = vt  + (size_t)4194304;             // 4096*1024
  u16* xb  = ao  + (size_t)4194304;             // 4096*1024
  u16* wqb = xb  + (size_t)4194304;             // 3072*1024
  u16* wob = wqb + (size_t)3145728;             // 1024*1024

  // 0. one-time fp32 -> bf16 conversion of inputs
  cvt_f32_bf16<<<2048, 256, 0, stream>>>(x, xb, 524288);
  cvt_f32_bf16<<<1536, 256, 0, stream>>>(w_qkv, wqb, 393216);
  cvt_f32_bf16<<<512, 256, 0, stream>>>(w_o, wob, 131072);

  // 1. qkv(bf16 ws) = xb @ wqb^T; k/v cols also -> fp32 outputs
  gemm_bt<false, true><<<dim3(24, 32), 256, 0, stream>>>(
      xb, wqb, qkv, outk, outv, 4096, 3072, 1024);
  // 2. v -> v^T ws
  transpose_v<<<dim3(32, 32), 256, 0, stream>>>(qkv, vt);
  // 3. flash attention -> ao (bf16 ws)
  attn<<<dim3(16, 32), 256, 0, stream>>>(qkv, vt, ao);
  // 4. out(fp32) = ao @ wob^T
  gemm_bt<true, false><<<dim3(8, 32), 256, 0, stream>>>(
      ao, wob, out, nullptr, nullptr, 4096, 1024, 1024);
}